// Round 24
// baseline (66.894 us; speedup 1.0000x reference)
//
#include <hip/hip_runtime.h>

#define KLEN 1024
#define HOP 512
#define NW 511
#define NB 4
#define NC 16
#define NBINS 513
#define NSAMP 262144
#define MAPN (NC * KLEN)

// ws layout (bytes): map float4[MAPN] @0 | hann float[1024] @262144
#define WS_HANN 262144

// LDS dump layout: bin kk = k1 + 16*k2  ->  addr = k1 + 17*k2  (<=2-way banks)
#define DIDX(kk) (((kk) & 15) + 17 * ((kk) >> 4))

#define CMULBF(ar,ai,br,bi,wr,wi) { float tr_=(ar)-(br), ti_=(ai)-(bi); \
    (ar)+=(br); (ai)+=(bi); (br)=tr_*(wr)-ti_*(wi); (bi)=tr_*(wi)+ti_*(wr); }
#define CMUL(xr,xi,yr,yi,or_,oi_) { (or_)=(xr)*(yr)-(xi)*(yi); (oi_)=(xr)*(yi)+(xi)*(yr); }

__global__ __launch_bounds__(256) void warpmap_kernel(
    const float* __restrict__ dlnf,
    float4* __restrict__ map, float* __restrict__ g_hann)
{
    const int c = blockIdx.x;
    const double TWO_PI = 6.283185307179586476925287;
    const double beta = 2.0 * (double)dlnf[c];
    const bool small = fabs(beta) < 1e-8;
    const double bs = small ? 1e-8 : beta;
    const double e2b = exp(2.0 * bs);
    const double t_mid = small ? 0.0 : (log(1.0 + 0.5 * (e2b - 1.0)) / bs - 1.0);

    for (int j = threadIdx.x; j < KLEN; j += 256) {
        double tau = 2.0 * (double)j / 1024.0 - 1.0;
        double ts, jac;
        if (small) { ts = tau; jac = 1.0; }
        else {
            ts = log(1.0 + (tau + 1.0) * 0.5 * (e2b - 1.0)) / bs - 1.0;
            jac = exp(-bs * (ts - t_mid));
        }
        double idxf = 512.0 * (ts + 1.0);
        int lo = (int)idxf;
        lo = lo < 0 ? 0 : (lo > 1022 ? 1022 : lo);
        map[c * KLEN + j] = make_float4(__int_as_float(lo),
                                        (float)(idxf - (double)lo),
                                        (float)jac, 0.0f);
    }
    if (c == 0) {
        for (int k = threadIdx.x; k < KLEN; k += 256)
            g_hann[k] = (float)(0.5 * (1.0 - cos(TWO_PI * (double)k / 1024.0)));
    }
}

__global__ __launch_bounds__(256) void dechirp_regfft_kernel(
    const float* __restrict__ x,
    const float4* __restrict__ map,
    const float* __restrict__ g_hann,
    float* __restrict__ out)
{
    __shared__ float wd[KLEN];
    __shared__ float dre[4][17 * 64], dim_[4][17 * 64];

    const int tid  = threadIdx.x;
    const int lane = tid & 63;
    const int wv   = tid >> 6;
    const int blin = blockIdx.x;            // (b*NW + w)*2 + half
    const int hlf  = blin & 1;
    const int w    = (blin >> 1) % NW;
    const int b    = blin / (2 * NW);
    const int q    = hlf * 4 + wv;          // chirp pair of this wave
    const int c0 = 2 * q, c1 = 2 * q + 1;

    // Stage windowed frame (shared by all 4 waves) — the only block barrier
    const float* xrow = x + (size_t)b * NSAMP + (size_t)w * HOP;
    for (int k = tid; k < KLEN; k += 256)
        wd[k] = xrow[k] * g_hann[k];
    __syncthreads();

    // ---- Phase 1: resample both chirps into registers: z[t] = resamp[lane + 64 t]
    float zr[16], zi[16];
    const float4* m0 = map + c0 * KLEN;
    const float4* m1 = map + c1 * KLEN;
    #pragma unroll
    for (int t = 0; t < 16; ++t) {
        int j = lane + (t << 6);
        float4 a = m0[j];
        int   a0 = __float_as_int(a.x);
        zr[t] = (wd[a0] * (1.0f - a.y) + wd[a0 + 1] * a.y) * a.z;
        float4 bb = m1[j];
        int   a1 = __float_as_int(bb.x);
        zi[t] = (wd[a1] * (1.0f - bb.y) + wd[a1 + 1] * bb.y) * bb.z;
    }

    // ---- Phase 2: 16-point DIF FFT in registers (n1 axis), twiddles literal
    {
        constexpr float W16R[8] = { 1.0f, 0.9238795325f, 0.7071067812f, 0.3826834324f,
                                    0.0f,-0.3826834324f,-0.7071067812f,-0.9238795325f };
        constexpr float W16I[8] = { 0.0f,-0.3826834324f,-0.7071067812f,-0.9238795325f,
                                   -1.0f,-0.9238795325f,-0.7071067812f,-0.3826834324f };
        constexpr float W8R[4]  = { 1.0f, 0.7071067812f, 0.0f,-0.7071067812f };
        constexpr float W8I[4]  = { 0.0f,-0.7071067812f,-1.0f,-0.7071067812f };
        #pragma unroll
        for (int j = 0; j < 8; ++j) CMULBF(zr[j],zi[j],zr[j+8],zi[j+8],W16R[j],W16I[j]);
        #pragma unroll
        for (int g = 0; g < 2; ++g)
            #pragma unroll
            for (int j = 0; j < 4; ++j)
                CMULBF(zr[g*8+j],zi[g*8+j],zr[g*8+j+4],zi[g*8+j+4],W8R[j],W8I[j]);
        #pragma unroll
        for (int g = 0; g < 4; ++g) {
            CMULBF(zr[g*4],zi[g*4],zr[g*4+2],zi[g*4+2],1.0f,0.0f);
            CMULBF(zr[g*4+1],zi[g*4+1],zr[g*4+3],zi[g*4+3],0.0f,-1.0f);
        }
        #pragma unroll
        for (int g = 0; g < 8; ++g)
            CMULBF(zr[g*2],zi[g*2],zr[g*2+1],zi[g*2+1],1.0f,0.0f);
    }

    // ---- Phase 3: twiddle W1024^{lane*k1}; reg r holds k1 = brev4(r)
    {
        float s1, c1;
        __sincosf((float)lane * (-6.283185307179586f / 1024.0f), &s1, &c1);
        float pr[16], pi_[16];
        pr[0]=1.0f; pi_[0]=0.0f; pr[1]=c1; pi_[1]=s1;
        CMUL(pr[1],pi_[1],pr[1],pi_[1],pr[2],pi_[2]);
        CMUL(pr[1],pi_[1],pr[2],pi_[2],pr[3],pi_[3]);
        CMUL(pr[2],pi_[2],pr[2],pi_[2],pr[4],pi_[4]);
        CMUL(pr[1],pi_[1],pr[4],pi_[4],pr[5],pi_[5]);
        CMUL(pr[2],pi_[2],pr[4],pi_[4],pr[6],pi_[6]);
        CMUL(pr[3],pi_[3],pr[4],pi_[4],pr[7],pi_[7]);
        CMUL(pr[4],pi_[4],pr[4],pi_[4],pr[8],pi_[8]);
        #pragma unroll
        for (int t = 1; t < 8; ++t)
            CMUL(pr[t],pi_[t],pr[8],pi_[8],pr[t+8],pi_[t+8]);
        constexpr int BREV4[16] = {0,8,4,12,2,10,6,14,1,9,5,13,3,11,7,15};
        #pragma unroll
        for (int r = 1; r < 16; ++r) {
            const int k1 = BREV4[r];
            float tr; CMUL(zr[r],zi[r],pr[k1],pi_[k1],tr,zi[r]);
            zr[r] = tr;
        }
    }

    // ---- Phase 4: 64-point DIF FFT across lanes via shfl_xor (no LDS, no barriers)
    #pragma unroll
    for (int st = 0; st < 6; ++st) {
        const int half = 32 >> st;
        const int j = lane & (half - 1);
        float sw = 0.0f, cw = 1.0f;
        if (half > 1)
            __sincosf((float)j * (-6.283185307179586f / (float)(2 * half)), &sw, &cw);
        const bool hi = (lane & half) != 0;
        #pragma unroll
        for (int r = 0; r < 16; ++r) {
            float prr = __shfl_xor(zr[r], half);
            float pii = __shfl_xor(zi[r], half);
            float sr = zr[r] + prr, si = zi[r] + pii;
            float dr = prr - zr[r], di = pii - zi[r];
            float tr = dr * cw - di * sw, ti = dr * sw + di * cw;
            zr[r] = hi ? tr : sr;
            zi[r] = hi ? ti : si;
        }
    }

    // ---- Dump to LDS in natural bin order: lane l, reg r -> bin brev4(r) + 16*brev6(l)
    {
        float* Lr = dre[wv];
        float* Li = dim_[wv];
        const int K2 = (int)(__brev((unsigned)lane) >> 26);   // brev6(lane)
        const int base = 17 * K2;
        constexpr int BREV4[16] = {0,8,4,12,2,10,6,14,1,9,5,13,3,11,7,15};
        #pragma unroll
        for (int r = 0; r < 16; ++r) {
            Lr[base + BREV4[r]] = zr[r];
            Li[base + BREV4[r]] = zi[r];
        }
    }
    __builtin_amdgcn_wave_barrier();

    // ---- Unpack real parts of both chirps; coalesced global write
    {
        const float* Lr = dre[wv];
        const float* Li = dim_[wv];
        size_t obase0 = (((size_t)b * NW + w) * NC + c0) * NBINS;
        size_t obase1 = obase0 + NBINS;
        #pragma unroll
        for (int t = 0; t < 9; ++t) {
            int k = lane + (t << 6);
            if (k < NBINS) {
                int rk = (KLEN - k) & (KLEN - 1);
                float fr = 0.5f * (Lr[DIDX(k)] + Lr[DIDX(rk)]);
                float gr = 0.5f * (Li[DIDX(k)] + Li[DIDX(rk)]);
                out[obase0 + k] = fr;
                out[obase1 + k] = gr;
            }
        }
    }
}

extern "C" void kernel_launch(void* const* d_in, const int* in_sizes, int n_in,
                              void* d_out, int out_size, void* d_ws, size_t ws_size,
                              hipStream_t stream) {
    const float* x = nullptr;
    const float* dlnf = nullptr;
    for (int i = 0; i < n_in; ++i) {
        if (in_sizes[i] == NB * NSAMP)      x = (const float*)d_in[i];
        else if (in_sizes[i] == NC)         dlnf = (const float*)d_in[i];
    }
    if (!x)    x    = (const float*)d_in[0];
    if (!dlnf) dlnf = (const float*)d_in[1];
    float* out = (float*)d_out;

    char* ws = (char*)d_ws;
    float4* map    = (float4*)ws;
    float*  g_hann = (float*)(ws + WS_HANN);

    warpmap_kernel<<<NC, 256, 0, stream>>>(dlnf, map, g_hann);

    const int nblocks = NB * NW * 2;  // 4088 blocks, 4 waves, 1 chirp-pair per wave
    dechirp_regfft_kernel<<<nblocks, 256, 0, stream>>>(x, map, g_hann, out);
}